// Round 7
// baseline (407.301 us; speedup 1.0000x reference)
//
#include <hip/hip_runtime.h>

#define NPTS 8192

typedef __bf16 bf16x8 __attribute__((ext_vector_type(8)));
typedef float f32x4 __attribute__((ext_vector_type(4)));

// DIAGNOSTIC ROUND (resubmit of R5 design after container flake): dft runs
// nrep=8x (idempotent; reps 2+ L3-fed) so it rises above the ~80us
// harness-fill cutoff and appears in rocprof top-5 with full counters.
// synth at 1x. Revert dft nrep next round.
//
// ws layout (floats): yc [0,131072) ; wtr [131072,196608) ; wti [196608,262144)
// d_out scratch layout (floats):
//   Xp  [0, 4194304): partial DFT, Xp[((seg*16+k)*2+c)*4096 + row], seg<32,
//       c=0 re / 1 im, row = b*64 + in_ch
//   bas [4194304, 4456448): bf16 basis tables as ushort bits (dft frag order):
//       idx = ((ct*256 + gk)*64 + lane)*8 + j -> mode m=(lane&15),
//       n = gk*32 + ((lane>>4)&3)*8 + j ; ct=0: cos, ct=1: -sin
// Order: prep writes bas -> dft reads bas, writes Xp -> mix reads Xp ->
// synth reads only yc/registers and overwrites all of d_out (no race).

__device__ __forceinline__ void split8(const float* v, bf16x8& h, bf16x8& l) {
#pragma unroll
    for (int j = 0; j < 8; ++j) {
        __bf16 hb = (__bf16)v[j];            // RNE hi
        float lo = v[j] - (float)hb;         // exact residual
        h[j] = hb;
        l[j] = (__bf16)lo;                   // RNE lo
    }
}

__global__ __launch_bounds__(256) void prep_kernel(const float* __restrict__ wr,
                                                   const float* __restrict__ wi,
                                                   float* __restrict__ wtr,
                                                   float* __restrict__ wti,
                                                   ushort* __restrict__ bas) {
    const int bid = blockIdx.x, t = threadIdx.x;
    if (bid < 256) {
        int idx = bid * 256 + t;                    // [0, 65536)
        int i = idx >> 10, o = (idx >> 4) & 63, k = idx & 15;
        int dst = k * 4096 + i * 64 + o;
        wtr[dst] = wr[idx];
        wti[dst] = wi[idx];
    } else {
        int e = (bid - 256) * 256 + t;              // [0, 262144)
        int j = e & 7;
        int lane = (e >> 3) & 63;
        int gk = (e >> 9) & 255;
        int ct = e >> 17;                           // 0: cos tile, 1: -sin tile
        int m = lane & 15;
        int n = gk * 32 + ((lane >> 4) & 3) * 8 + j;
        int p = (m * n) & 8191;
        float a = (float)p * (1.0f / 4096.0f);
        float v = ct ? -sinpif(a) : cospif(a);
        __bf16 hb = (__bf16)v;
        float lo = v - (float)hb;
        __bf16 lb = (__bf16)lo;
        bas[e] = __builtin_bit_cast(ushort, hb);
        bas[262144 + e] = __builtin_bit_cast(ushort, lb);
    }
}

// Stage 1: truncated DFT as MFMA GEMM.
// grid 2048 = 64 row-blocks(64 rows) x 32 k-segments(256 pts) -> up to 8
// blocks/CU; lean per-kstep body (~85 VGPR) so TLP hides HBM latency.
__global__ __launch_bounds__(256, 4) void dft_kernel(const float* __restrict__ x,
                                                     const ushort* __restrict__ bas,
                                                     float* __restrict__ Xp,
                                                     int nrep) {
    const int t = threadIdx.x;
    const int lane = t & 63, w = t >> 6;
    const int rb = blockIdx.x >> 5, seg = blockIdx.x & 31;
    const int rowq = lane >> 4;                     // 0..3 (k-slot quarter)
    const int row = rb * 64 + w * 16 + (lane & 15);
    const float* xp = x + (size_t)row * NPTS + seg * 256 + rowq * 8;
    const bf16x8* bh = (const bf16x8*)bas;
    const bf16x8* bl = (const bf16x8*)(bas + 262144);
    const int gk0 = seg * 8;

#pragma unroll 1
    for (int rep = 0; rep < nrep; ++rep) {
        f32x4 acc0 = {0.f, 0.f, 0.f, 0.f};         // cos tile  (re)
        f32x4 acc1 = {0.f, 0.f, 0.f, 0.f};         // -sin tile (im)

        float4 xa = *(const float4*)xp;
        float4 xb = *(const float4*)(xp + 4);
        bf16x8 c0h = bh[gk0 * 64 + lane];
        bf16x8 c1h = bh[(256 + gk0) * 64 + lane];
        bf16x8 c0l = bl[gk0 * 64 + lane];
        bf16x8 c1l = bl[(256 + gk0) * 64 + lane];

#pragma unroll 1
        for (int ks = 0; ks < 8; ++ks) {
            float v[8];
            v[0] = xa.x; v[1] = xa.y; v[2] = xa.z; v[3] = xa.w;
            v[4] = xb.x; v[5] = xb.y; v[6] = xb.z; v[7] = xb.w;
            bf16x8 ah, al;
            split8(v, ah, al);

            float4 nxa, nxb;
            bf16x8 n0h, n1h, n0l, n1l;
            if (ks < 7) {                           // depth-1 prefetch
                const float* xq = xp + (ks + 1) * 32;
                nxa = *(const float4*)xq;
                nxb = *(const float4*)(xq + 4);
                int gk = gk0 + ks + 1;
                n0h = bh[gk * 64 + lane];
                n1h = bh[(256 + gk) * 64 + lane];
                n0l = bl[gk * 64 + lane];
                n1l = bl[(256 + gk) * 64 + lane];
            }

            // D = xh*bh + xl*bh + xh*bl   (drop lo*lo, ~2^-18 rel)
            acc0 = __builtin_amdgcn_mfma_f32_16x16x32_bf16(ah, c0h, acc0, 0, 0, 0);
            acc1 = __builtin_amdgcn_mfma_f32_16x16x32_bf16(ah, c1h, acc1, 0, 0, 0);
            acc0 = __builtin_amdgcn_mfma_f32_16x16x32_bf16(al, c0h, acc0, 0, 0, 0);
            acc1 = __builtin_amdgcn_mfma_f32_16x16x32_bf16(al, c1h, acc1, 0, 0, 0);
            acc0 = __builtin_amdgcn_mfma_f32_16x16x32_bf16(ah, c0l, acc0, 0, 0, 0);
            acc1 = __builtin_amdgcn_mfma_f32_16x16x32_bf16(ah, c1l, acc1, 0, 0, 0);

            if (ks < 7) {
                xa = nxa; xb = nxb;
                c0h = n0h; c1h = n1h; c0l = n0l; c1l = n1l;
            }
        }

        const int k = lane & 15;
        const int rbase = rb * 64 + w * 16 + rowq * 4;  // 4 consecutive rows
        *(f32x4*)&Xp[(size_t)((seg * 16 + k) * 2 + 0) * 4096 + rbase] = acc0;
        *(f32x4*)&Xp[(size_t)((seg * 16 + k) * 2 + 1) * 4096 + rbase] = acc1;
    }
}

// Stage 2: channel mix. grid 256 = 16 modes x 16 batch-16ths (4 batches each).
__global__ __launch_bounds__(256) void mix_kernel(const float* __restrict__ Xp,
                                                  const float* __restrict__ wtr,
                                                  const float* __restrict__ wti,
                                                  float* __restrict__ yc) {
    __shared__ float xre[256], xim[256];
    __shared__ float wlr[4096], wli[4096];
    const int t = threadIdx.x;
    const int k = blockIdx.x & 15, bq = blockIdx.x >> 4;
    {
        int row = bq * 256 + t;
        float re = 0.f, im = 0.f;
#pragma unroll
        for (int s = 0; s < 32; ++s) {              // 32 K-segments now
            re += Xp[((s * 16 + k) * 2 + 0) * 4096 + row];
            im += Xp[((s * 16 + k) * 2 + 1) * 4096 + row];
        }
        xre[t] = re;
        xim[t] = im;
#pragma unroll
        for (int j = 0; j < 4; ++j) {
            ((float4*)wlr)[t + j * 256] = ((const float4*)(wtr + k * 4096))[t + j * 256];
            ((float4*)wli)[t + j * 256] = ((const float4*)(wti + k * 4096))[t + j * 256];
        }
    }
    __syncthreads();
    const int bt = t >> 6;                      // local batch 0..3 (= wave id)
    const int o = t & 63;                       // out_ch
    float accr = 0.f, acci = 0.f;
#pragma unroll 8
    for (int i = 0; i < 64; ++i) {
        float xr = xre[bt * 64 + i], xi = xim[bt * 64 + i];   // broadcast
        float wr = wlr[i * 64 + o], wi = wli[i * 64 + o];     // stride-1
        accr += xr * wr - xi * wi;
        acci += xr * wi + xi * wr;
    }
    const float invn = 1.0f / 8192.0f;
    int row2 = (bq * 4 + bt) * 64 + o;
    if (k == 0) {
        yc[row2 * 32]      = accr * invn;
        yc[row2 * 32 + 16] = 0.f;
    } else {
        yc[row2 * 32 + k]      = 2.f * accr * invn;
        yc[row2 * 32 + 16 + k] = -2.f * acci * invn;
    }
}

// Stage 3: synthesis as MFMA GEMM (write-roofline-bound per R5 counters).
__global__ __launch_bounds__(256) void synth_kernel(const float* __restrict__ yc,
                                                    float* __restrict__ out) {
    const int t = threadIdx.x;
    const int lane = t & 63, w = t >> 6;
    const int rg = blockIdx.x >> 2, nq = blockIdx.x & 3;
    const int rowbase = rg * 16;
    const int col = lane & 15;                  // A: n within tile / B: out-row
    const int q = lane >> 4;                    // k-slot quarter
    const int fb = (q & 1) * 8;                 // frequency base of this quarter
    const bool isSin = q >= 2;                  // slots 16..31 are sin coefs

    bf16x8 bhf, blf;
    {
        float v[8];
        const float* cp = yc + (rowbase + col) * 32 + q * 8;
        *(float4*)&v[0] = *(const float4*)cp;
        *(float4*)&v[4] = *(const float4*)(cp + 4);
        split8(v, bhf, blf);
    }

    float val[8], aux[8], cd[8], sd[8];
    const int nbase = nq * 2048 + w * 512;
    {
        int n = nbase + col;
#pragma unroll
        for (int j = 0; j < 8; ++j) {
            int fj = fb + j;
            float a = (float)((fj * n) & 8191) * (1.0f / 4096.0f);
            float c = cospif(a), s = sinpif(a);
            val[j] = isSin ? s : c;
            aux[j] = isSin ? -c : s;
            float b = (float)fj * (1.0f / 256.0f);   // delta = 2*pi*16*fj/8192
            cd[j] = cospif(b);
            sd[j] = sinpif(b);
        }
    }

    float* op = out + (size_t)(rowbase + col) * NPTS + nbase + q * 4;
#pragma unroll 4
    for (int it = 0; it < 32; ++it) {
        bf16x8 ah, al;
        split8(val, ah, al);
        f32x4 acc = {0.f, 0.f, 0.f, 0.f};
        acc = __builtin_amdgcn_mfma_f32_16x16x32_bf16(ah, bhf, acc, 0, 0, 0);
        acc = __builtin_amdgcn_mfma_f32_16x16x32_bf16(al, bhf, acc, 0, 0, 0);
        acc = __builtin_amdgcn_mfma_f32_16x16x32_bf16(ah, blf, acc, 0, 0, 0);
        *(f32x4*)(op + it * 16) = acc;
#pragma unroll
        for (int j = 0; j < 8; ++j) {
            float nv = val[j] * cd[j] - aux[j] * sd[j];
            float na = aux[j] * cd[j] + val[j] * sd[j];
            val[j] = nv;
            aux[j] = na;
        }
    }
}

extern "C" void kernel_launch(void* const* d_in, const int* in_sizes, int n_in,
                              void* d_out, int out_size, void* d_ws, size_t ws_size,
                              hipStream_t stream) {
    const float* x  = (const float*)d_in[0];
    const float* wr = (const float*)d_in[1];
    const float* wi = (const float*)d_in[2];
    float* out = (float*)d_out;
    float* ws  = (float*)d_ws;
    float* yc  = ws;
    float* wtr = ws + 131072;
    float* wti = ws + 196608;
    float* Xp  = out;                                // 16 MB scratch
    ushort* bas = (ushort*)(out + 4194304);          // 1 MB bf16 basis tables

    prep_kernel<<<1280, 256, 0, stream>>>(wr, wi, wtr, wti, bas);
    dft_kernel<<<2048, 256, 0, stream>>>(x, bas, Xp, 8);     // DIAG x8
    mix_kernel<<<256, 256, 0, stream>>>(Xp, wtr, wti, yc);
    synth_kernel<<<1024, 256, 0, stream>>>(yc, out);
}